// Round 1
// 463.656 us; speedup vs baseline: 1.0105x; 1.0105x over previous
//
#include <hip/hip_runtime.h>
#include <math.h>

// Problem constants
#define NMASK 1024
#define HH 256
#define WW 256
#define HW 65536            // H*W
#define OUT_ELEMS 67108864  // NMASK*HW

// ---------------------------------------------------------------------------
// Kernel A: per-mask stats + score (fused). 1 block per mask, 256 threads,
// 64 float4/thread. Computes hi=count(>1), lo=count(>-1), bbox of (>0),
// then the block leader derives stability/validity/score/box directly.
// score[m] = valid ? iou : -inf  (so validity is encoded in the score).
// ---------------------------------------------------------------------------
__global__ __launch_bounds__(256) void stats_kernel(
    const float* __restrict__ logits, const float* __restrict__ iou_preds,
    float* __restrict__ score, float* __restrict__ boxf,
    float* __restrict__ boxes_out) {
  const int m = blockIdx.x;
  const int t = threadIdx.x;
  const float4* __restrict__ p = (const float4*)(logits + (size_t)m * HW);

  int hi = 0, lo = 0;
  int miny = HH, maxy = -1, minx = WW, maxx = -1;

  for (int k = 0; k < 64; ++k) {
    const int f = k * 256 + t;          // float4 index within mask [0,16384)
    const float4 v = p[f];
    const int y = f >> 6;               // 64 float4 per row
    const int x0 = (f & 63) << 2;

    const bool p0 = v.x > 0.0f, p1 = v.y > 0.0f, p2 = v.z > 0.0f, p3 = v.w > 0.0f;
    hi += (v.x > 1.0f) + (v.y > 1.0f) + (v.z > 1.0f) + (v.w > 1.0f);
    lo += (v.x > -1.0f) + (v.y > -1.0f) + (v.z > -1.0f) + (v.w > -1.0f);
    if (p0 | p1 | p2 | p3) {
      miny = min(miny, y);
      maxy = max(maxy, y);
      if (p0) { minx = min(minx, x0);     maxx = max(maxx, x0); }
      if (p1) { minx = min(minx, x0 + 1); maxx = max(maxx, x0 + 1); }
      if (p2) { minx = min(minx, x0 + 2); maxx = max(maxx, x0 + 2); }
      if (p3) { minx = min(minx, x0 + 3); maxx = max(maxx, x0 + 3); }
    }
  }

  // wave (64-lane) reduction
  for (int off = 32; off; off >>= 1) {
    hi += __shfl_down(hi, off);
    lo += __shfl_down(lo, off);
    miny = min(miny, __shfl_down(miny, off));
    maxy = max(maxy, __shfl_down(maxy, off));
    minx = min(minx, __shfl_down(minx, off));
    maxx = max(maxx, __shfl_down(maxx, off));
  }

  __shared__ int red[4][6];
  const int wv = t >> 6, ln = t & 63;
  if (ln == 0) {
    red[wv][0] = hi;  red[wv][1] = lo;
    red[wv][2] = miny; red[wv][3] = maxy;
    red[wv][4] = minx; red[wv][5] = maxx;
  }
  __syncthreads();
  if (t == 0) {
    int H2 = 0, L2 = 0, mny = HH, mxy = -1, mnx = WW, mxx = -1;
    for (int w = 0; w < 4; ++w) {
      H2 += red[w][0]; L2 += red[w][1];
      mny = min(mny, red[w][2]); mxy = max(mxy, red[w][3]);
      mnx = min(mnx, red[w][4]); mxx = max(mxx, red[w][5]);
    }
    const float stab = (float)H2 / fmaxf((float)L2, 1.0f);
    const float iv = iou_preds[m];
    const bool valid = (iv > 0.88f) && (stab >= 0.95f);

    float4 b;
    if (mxy < 0) { b.x = b.y = b.z = b.w = 0.0f; }
    else { b.x = (float)mnx; b.y = (float)mny; b.z = (float)mxx; b.w = (float)mxy; }

    ((float4*)boxf)[m] = b;
    ((float4*)boxes_out)[m] = b;
    score[m] = valid ? iv : -INFINITY;
  }
}

// ---------------------------------------------------------------------------
// Kernel B: fused rank + suppression-matrix + greedy NMS + scatter.
// One block, 1024 threads, everything in LDS (~62 KB).
//   phase 1: compact valid indices (score > -inf), count nv
//   phase 2: rank valid masks among valid only (nv^2 compares, stable ties)
//   phase 3: suppression bit-matrix rows for sorted rows < min(nv,256)
//   phase 4: single-wave greedy NMS over keep bits (lanes 0..15 hold 1024 bits)
//   phase 5: scatter keep/gated back to original order
// ---------------------------------------------------------------------------
__global__ __launch_bounds__(1024) void nms_fused(
    const float* __restrict__ score_g, const float* __restrict__ boxf,
    const float* __restrict__ iou_preds, float* __restrict__ gated,
    float* __restrict__ keep_out) {
  __shared__ float s_score[NMASK];
  __shared__ float4 s_bo[NMASK];                 // boxes, original order
  __shared__ int s_sidx[NMASK];                  // sorted pos -> orig idx
  __shared__ int s_rank[NMASK];                  // orig idx -> sorted pos
  __shared__ unsigned long long s_rows[256 * 16];// supp matrix; aliased as cidx early
  __shared__ int s_wcnt[16];
  __shared__ int s_woff[16];
  __shared__ int s_nv;
  __shared__ unsigned long long s_keepw[16];

  const int t = threadIdx.x;
  const int wv = t >> 6, lane = t & 63;

  // ---- phase 1: load + valid compaction (index order) ----
  const float sc = score_g[t];
  s_score[t] = sc;
  s_bo[t] = ((const float4*)boxf)[t];
  const bool valid = sc != -INFINITY;
  const unsigned long long vb = __ballot(valid);
  if (lane == 0) s_wcnt[wv] = __popcll(vb);
  __syncthreads();
  if (t == 0) {
    int acc = 0;
    for (int w = 0; w < 16; ++w) { s_woff[w] = acc; acc += s_wcnt[w]; }
    s_nv = acc;
  }
  __syncthreads();
  const int nv = s_nv;
  int* cidx = (int*)s_rows;  // alias: used only before matrix phase
  const unsigned long long below = lane ? (~0ull >> (64 - lane)) : 0ull;
  const int vbelow = s_woff[wv] + __popcll(vb & below);
  if (valid) {
    cidx[vbelow] = t;
  } else {
    // invalid masks: sorted after all valid, in index order (matches stable
    // argsort of -inf ties; their relative order never affects results)
    const int r = nv + (t - vbelow);
    s_rank[t] = r;
    s_sidx[r] = t;
  }
  __syncthreads();

  // ---- phase 2: rank valid masks (score desc, index asc on ties) ----
  if (t < nv) {
    const int i = cidx[t];
    const float si = s_score[i];
    int r = 0;
    for (int q = 0; q < nv; ++q) {
      const int j = cidx[q];
      const float sj = s_score[j];
      r += (sj > si) || (sj == si && j < i);
    }
    s_rank[i] = r;
    s_sidx[r] = i;
  }
  __syncthreads();  // done with cidx -> s_rows reusable

  // ---- phase 3: suppression bit-matrix in LDS ----
  const int R = min(nv, 256);
  const int nw = (nv + 63) >> 6;
  for (int k = t; k < R * 16; k += 1024) s_rows[k] = 0ull;
  __syncthreads();
  for (int i = wv; i < R; i += 16) {
    const float4 a = s_bo[s_sidx[i]];
    const float aa = fmaxf(a.z - a.x, 0.0f) * fmaxf(a.w - a.y, 0.0f);
    for (int cw = 0; cw < nw; ++cw) {
      const int col = cw * 64 + lane;
      bool supp = false;
      if (col < nv && col > i) {
        const float4 b = s_bo[s_sidx[col]];
        const float x0 = fmaxf(a.x, b.x), y0 = fmaxf(a.y, b.y);
        const float x1 = fminf(a.z, b.z), y1 = fminf(a.w, b.w);
        const float inter = fmaxf(x1 - x0, 0.0f) * fmaxf(y1 - y0, 0.0f);
        const float ab = fmaxf(b.z - b.x, 0.0f) * fmaxf(b.w - b.y, 0.0f);
        const float iou = inter / fmaxf(aa + ab - inter, 1e-6f);
        supp = iou > 0.7f;
      }
      const unsigned long long bal = __ballot(supp);
      if (lane == 0) s_rows[i * 16 + cw] = bal;
    }
  }
  __syncthreads();

  // ---- phase 4: greedy NMS on wave 0 (lanes 0..15 hold the 1024 keep bits) --
  if (wv == 0) {
    unsigned long long keepword;
    {
      const int base = lane * 64;
      keepword = (nv >= base + 64) ? ~0ull
               : (nv <= base ? 0ull : ((1ull << (nv - base)) - 1ull));
    }
    for (int i = 0; i < nv; ++i) {
      const unsigned long long kw = __shfl(keepword, i >> 6, 64);  // uniform
      if (!((kw >> (i & 63)) & 1ull)) continue;
      if (i < 256) {
        if (lane < 16) keepword &= ~s_rows[i * 16 + lane];
      } else {
        // rare fallback (nv > 256): recompute row on demand
        const float4 a = s_bo[s_sidx[i]];
        const float aa = fmaxf(a.z - a.x, 0.0f) * fmaxf(a.w - a.y, 0.0f);
        unsigned long long clr = 0ull;
        for (int cw = 0; cw < nw; ++cw) {
          const int col = cw * 64 + lane;
          bool supp = false;
          if (col < nv && col > i) {
            const float4 b = s_bo[s_sidx[col]];
            const float x0 = fmaxf(a.x, b.x), y0 = fmaxf(a.y, b.y);
            const float x1 = fminf(a.z, b.z), y1 = fminf(a.w, b.w);
            const float inter = fmaxf(x1 - x0, 0.0f) * fmaxf(y1 - y0, 0.0f);
            const float ab = fmaxf(b.z - b.x, 0.0f) * fmaxf(b.w - b.y, 0.0f);
            supp = inter / fmaxf(aa + ab - inter, 1e-6f) > 0.7f;
          }
          const unsigned long long bal = __ballot(supp);
          if (lane == cw) clr = bal;
        }
        keepword &= ~clr;
      }
    }
    if (lane < 16) s_keepw[lane] = keepword;
  }
  __syncthreads();

  // ---- phase 5: scatter back to original order ----
  const int r = s_rank[t];
  const float kept = ((s_keepw[r >> 6] >> (r & 63)) & 1ull) ? 1.0f : 0.0f;
  keep_out[t] = kept;
  gated[t] = kept * iou_preds[t];
}

// ---------------------------------------------------------------------------
// Kernel C: out = sigmoid(logits) * gated. Zero-write fast path (no read)
// for gated==0 masks. 16 blocks per mask, 256 thr, 4 float4 per thread.
// ---------------------------------------------------------------------------
__global__ __launch_bounds__(256) void out_kernel(
    const float* __restrict__ logits, const float* __restrict__ gated,
    float* __restrict__ out) {
  const int b = blockIdx.x;
  const int m = b >> 4;
  const float g = gated[m];
  const size_t base4 = (size_t)m * 16384 + (size_t)(b & 15) * 1024;  // float4 units
  const float4* __restrict__ in4 = (const float4*)logits + base4;
  float4* __restrict__ o4 = (float4*)out + base4;
  const int t = threadIdx.x;
  if (g == 0.0f) {
    const float4 z = {0.0f, 0.0f, 0.0f, 0.0f};
    o4[t] = z; o4[t + 256] = z; o4[t + 512] = z; o4[t + 768] = z;
  } else {
#pragma unroll
    for (int k = 0; k < 4; ++k) {
      const float4 v = in4[t + k * 256];
      float4 r;
      r.x = g / (1.0f + __expf(-v.x));
      r.y = g / (1.0f + __expf(-v.y));
      r.z = g / (1.0f + __expf(-v.z));
      r.w = g / (1.0f + __expf(-v.w));
      o4[t + k * 256] = r;
    }
  }
}

// ---------------------------------------------------------------------------
extern "C" void kernel_launch(void* const* d_in, const int* in_sizes, int n_in,
                              void* d_out, int out_size, void* d_ws, size_t ws_size,
                              hipStream_t stream) {
  const float* logits = (const float*)d_in[0];
  const float* iou    = (const float*)d_in[1];

  float* out       = (float*)d_out;
  float* keep_out  = out + OUT_ELEMS;          // 1024 floats
  float* boxes_out = keep_out + NMASK;         // 4096 floats

  // workspace carve (24 KB)
  char* w = (char*)d_ws;
  float* score = (float*)(w);                  // 1024 f  -> 4096
  float* boxf  = (float*)(w + 4096);           // 4096 f  -> 20480 (16B aligned)
  float* gated = (float*)(w + 20480);          // 1024 f  -> 24576

  stats_kernel<<<NMASK, 256, 0, stream>>>(logits, iou, score, boxf, boxes_out);
  nms_fused<<<1, 1024, 0, stream>>>(score, boxf, iou, gated, keep_out);
  out_kernel<<<NMASK * 16, 256, 0, stream>>>(logits, gated, out);
}

// Round 3
// 456.586 us; speedup vs baseline: 1.0261x; 1.0155x over previous
//
#include <hip/hip_runtime.h>
#include <math.h>

// Problem constants
#define NMASK 1024
#define HH 256
#define WW 256
#define HW 65536            // H*W
#define OUT_ELEMS 67108864  // NMASK*HW

// Native 16B vector type (clang ext_vector) — accepted by
// __builtin_nontemporal_{load,store}, unlike HIP's float4 class.
typedef float vf4 __attribute__((ext_vector_type(4)));

// ---------------------------------------------------------------------------
// Kernel A: per-mask stats + score (fused). 1 block per mask, 256 threads,
// 64 float4/thread. Computes hi=count(>1), lo=count(>-1), bbox of (>0),
// then the block leader derives stability/validity/score/box directly.
// score[m] = valid ? iou : -inf  (so validity is encoded in the score).
// ---------------------------------------------------------------------------
__global__ __launch_bounds__(256) void stats_kernel(
    const float* __restrict__ logits, const float* __restrict__ iou_preds,
    float* __restrict__ score, float* __restrict__ boxf,
    float* __restrict__ boxes_out) {
  const int m = blockIdx.x;
  const int t = threadIdx.x;
  const float4* __restrict__ p = (const float4*)(logits + (size_t)m * HW);

  int hi = 0, lo = 0;
  int miny = HH, maxy = -1, minx = WW, maxx = -1;

  for (int k = 0; k < 64; ++k) {
    const int f = k * 256 + t;          // float4 index within mask [0,16384)
    const float4 v = p[f];
    const int y = f >> 6;               // 64 float4 per row
    const int x0 = (f & 63) << 2;

    const bool p0 = v.x > 0.0f, p1 = v.y > 0.0f, p2 = v.z > 0.0f, p3 = v.w > 0.0f;
    hi += (v.x > 1.0f) + (v.y > 1.0f) + (v.z > 1.0f) + (v.w > 1.0f);
    lo += (v.x > -1.0f) + (v.y > -1.0f) + (v.z > -1.0f) + (v.w > -1.0f);
    if (p0 | p1 | p2 | p3) {
      miny = min(miny, y);
      maxy = max(maxy, y);
      if (p0) { minx = min(minx, x0);     maxx = max(maxx, x0); }
      if (p1) { minx = min(minx, x0 + 1); maxx = max(maxx, x0 + 1); }
      if (p2) { minx = min(minx, x0 + 2); maxx = max(maxx, x0 + 2); }
      if (p3) { minx = min(minx, x0 + 3); maxx = max(maxx, x0 + 3); }
    }
  }

  // wave (64-lane) reduction
  for (int off = 32; off; off >>= 1) {
    hi += __shfl_down(hi, off);
    lo += __shfl_down(lo, off);
    miny = min(miny, __shfl_down(miny, off));
    maxy = max(maxy, __shfl_down(maxy, off));
    minx = min(minx, __shfl_down(minx, off));
    maxx = max(maxx, __shfl_down(maxx, off));
  }

  __shared__ int red[4][6];
  const int wv = t >> 6, ln = t & 63;
  if (ln == 0) {
    red[wv][0] = hi;  red[wv][1] = lo;
    red[wv][2] = miny; red[wv][3] = maxy;
    red[wv][4] = minx; red[wv][5] = maxx;
  }
  __syncthreads();
  if (t == 0) {
    int H2 = 0, L2 = 0, mny = HH, mxy = -1, mnx = WW, mxx = -1;
    for (int w = 0; w < 4; ++w) {
      H2 += red[w][0]; L2 += red[w][1];
      mny = min(mny, red[w][2]); mxy = max(mxy, red[w][3]);
      mnx = min(mnx, red[w][4]); mxx = max(mxx, red[w][5]);
    }
    const float stab = (float)H2 / fmaxf((float)L2, 1.0f);
    const float iv = iou_preds[m];
    const bool valid = (iv > 0.88f) && (stab >= 0.95f);

    float4 b;
    if (mxy < 0) { b.x = b.y = b.z = b.w = 0.0f; }
    else { b.x = (float)mnx; b.y = (float)mny; b.z = (float)mxx; b.w = (float)mxy; }

    ((float4*)boxf)[m] = b;
    ((float4*)boxes_out)[m] = b;
    score[m] = valid ? iv : -INFINITY;
  }
}

// ---------------------------------------------------------------------------
// Kernel B: fused rank + suppression-matrix + greedy NMS + scatter.
// One block, 1024 threads, everything in LDS (~62 KB).
//   phase 1: compact valid indices (score > -inf), count nv
//   phase 2: rank valid masks among valid only (nv^2 compares, stable ties)
//   phase 3: suppression bit-matrix rows for sorted rows < min(nv,256)
//   phase 4: single-wave greedy NMS with ctz-skip: serial iterations =
//            (#kept + #words), not nv — suppressed bits cost nothing.
//   phase 5: scatter keep/gated back to original order
// ---------------------------------------------------------------------------
__global__ __launch_bounds__(1024) void nms_fused(
    const float* __restrict__ score_g, const float* __restrict__ boxf,
    const float* __restrict__ iou_preds, float* __restrict__ gated,
    float* __restrict__ keep_out) {
  __shared__ float s_score[NMASK];
  __shared__ float4 s_bo[NMASK];                 // boxes, original order
  __shared__ int s_sidx[NMASK];                  // sorted pos -> orig idx
  __shared__ int s_rank[NMASK];                  // orig idx -> sorted pos
  __shared__ unsigned long long s_rows[256 * 16];// supp matrix; aliased as cidx early
  __shared__ int s_wcnt[16];
  __shared__ int s_woff[16];
  __shared__ int s_nv;
  __shared__ unsigned long long s_keepw[16];

  const int t = threadIdx.x;
  const int wv = t >> 6, lane = t & 63;

  // ---- phase 1: load + valid compaction (index order) ----
  const float sc = score_g[t];
  s_score[t] = sc;
  s_bo[t] = ((const float4*)boxf)[t];
  const bool valid = sc != -INFINITY;
  const unsigned long long vb = __ballot(valid);
  if (lane == 0) s_wcnt[wv] = __popcll(vb);
  __syncthreads();
  if (t == 0) {
    int acc = 0;
    for (int w = 0; w < 16; ++w) { s_woff[w] = acc; acc += s_wcnt[w]; }
    s_nv = acc;
  }
  __syncthreads();
  const int nv = s_nv;
  int* cidx = (int*)s_rows;  // alias: used only before matrix phase
  const unsigned long long below = lane ? (~0ull >> (64 - lane)) : 0ull;
  const int vbelow = s_woff[wv] + __popcll(vb & below);
  if (valid) {
    cidx[vbelow] = t;
  } else {
    // invalid masks: sorted after all valid, in index order (matches stable
    // argsort of -inf ties; their relative order never affects results)
    const int r = nv + (t - vbelow);
    s_rank[t] = r;
    s_sidx[r] = t;
  }
  __syncthreads();

  // ---- phase 2: rank valid masks (score desc, index asc on ties) ----
  if (t < nv) {
    const int i = cidx[t];
    const float si = s_score[i];
    int r = 0;
    for (int q = 0; q < nv; ++q) {
      const int j = cidx[q];
      const float sj = s_score[j];
      r += (sj > si) || (sj == si && j < i);
    }
    s_rank[i] = r;
    s_sidx[r] = i;
  }
  __syncthreads();  // done with cidx -> s_rows reusable

  // ---- phase 3: suppression bit-matrix in LDS ----
  const int R = min(nv, 256);
  const int nw = (nv + 63) >> 6;
  for (int k = t; k < R * 16; k += 1024) s_rows[k] = 0ull;
  __syncthreads();
  for (int i = wv; i < R; i += 16) {
    const float4 a = s_bo[s_sidx[i]];
    const float aa = fmaxf(a.z - a.x, 0.0f) * fmaxf(a.w - a.y, 0.0f);
    for (int cw = 0; cw < nw; ++cw) {
      const int col = cw * 64 + lane;
      bool supp = false;
      if (col < nv && col > i) {
        const float4 b = s_bo[s_sidx[col]];
        const float x0 = fmaxf(a.x, b.x), y0 = fmaxf(a.y, b.y);
        const float x1 = fminf(a.z, b.z), y1 = fminf(a.w, b.w);
        const float inter = fmaxf(x1 - x0, 0.0f) * fmaxf(y1 - y0, 0.0f);
        const float ab = fmaxf(b.z - b.x, 0.0f) * fmaxf(b.w - b.y, 0.0f);
        const float iou = inter / fmaxf(aa + ab - inter, 1e-6f);
        supp = iou > 0.7f;
      }
      const unsigned long long bal = __ballot(supp);
      if (lane == 0) s_rows[i * 16 + cw] = bal;
    }
  }
  __syncthreads();

  // ---- phase 4: greedy NMS on wave 0, ctz-skip over surviving bits ----
  // Bits only ever clear, and row i clears only columns > i, so an ascending
  // ctz scan with a "done below" watermark visits exactly the kept boxes in
  // the same order the naive i=0..nv-1 loop would.
  if (wv == 0) {
    unsigned long long keepword;  // lane l holds sorted bits [64l, 64l+64)
    {
      const int base = lane * 64;
      keepword = (nv >= base + 64) ? ~0ull
               : (nv <= base ? 0ull : ((1ull << (nv - base)) - 1ull));
    }
    const int nwords = (nv + 63) >> 6;
    for (int w = 0; w < nwords; ++w) {
      unsigned long long done = 0ull;  // bits of word w already visited
      for (;;) {
        const unsigned long long kw = __shfl(keepword, w, 64) & ~done;
        if (kw == 0ull) break;
        const int bit = __builtin_ctzll(kw);
        done = (bit == 63) ? ~0ull : ((2ull << bit) - 1ull);
        const int i = w * 64 + bit;  // this box is kept; suppress its row
        if (i < 256) {
          if (lane < 16) keepword &= ~s_rows[i * 16 + lane];
        } else {
          // rare fallback (nv > 256): recompute row on demand
          const float4 a = s_bo[s_sidx[i]];
          const float aa = fmaxf(a.z - a.x, 0.0f) * fmaxf(a.w - a.y, 0.0f);
          unsigned long long clr = 0ull;
          for (int cw = 0; cw < nw; ++cw) {
            const int col = cw * 64 + lane;
            bool supp = false;
            if (col < nv && col > i) {
              const float4 b = s_bo[s_sidx[col]];
              const float x0 = fmaxf(a.x, b.x), y0 = fmaxf(a.y, b.y);
              const float x1 = fminf(a.z, b.z), y1 = fminf(a.w, b.w);
              const float inter = fmaxf(x1 - x0, 0.0f) * fmaxf(y1 - y0, 0.0f);
              const float ab = fmaxf(b.z - b.x, 0.0f) * fmaxf(b.w - b.y, 0.0f);
              supp = inter / fmaxf(aa + ab - inter, 1e-6f) > 0.7f;
            }
            const unsigned long long bal = __ballot(supp);
            if (lane == cw) clr = bal;
          }
          keepword &= ~clr;
        }
      }
    }
    if (lane < 16) s_keepw[lane] = keepword;
  }
  __syncthreads();

  // ---- phase 5: scatter back to original order ----
  const int r = s_rank[t];
  const float kept = ((s_keepw[r >> 6] >> (r & 63)) & 1ull) ? 1.0f : 0.0f;
  keep_out[t] = kept;
  gated[t] = kept * iou_preds[t];
}

// ---------------------------------------------------------------------------
// Kernel C: out = sigmoid(logits) * gated. Zero-write fast path (no read)
// for gated==0 masks. 16 blocks per mask, 256 thr, 4 float4 per thread.
// Nontemporal stores: the 268 MB output stream is never re-read — keep it
// out of L2/L3 so logits (loaded by stats_kernel) can survive in L3 for the
// kept-mask re-reads. Nontemporal loads: read-once data.
// Uses native ext_vector vf4 (HIP float4 class is rejected by the builtin).
// ---------------------------------------------------------------------------
__global__ __launch_bounds__(256) void out_kernel(
    const float* __restrict__ logits, const float* __restrict__ gated,
    float* __restrict__ out) {
  const int b = blockIdx.x;
  const int m = b >> 4;
  const float g = gated[m];
  const size_t base4 = (size_t)m * 16384 + (size_t)(b & 15) * 1024;  // float4 units
  const vf4* __restrict__ in4 = (const vf4*)logits + base4;
  vf4* __restrict__ o4 = (vf4*)out + base4;
  const int t = threadIdx.x;
  if (g == 0.0f) {
    const vf4 z = {0.0f, 0.0f, 0.0f, 0.0f};
    __builtin_nontemporal_store(z, &o4[t]);
    __builtin_nontemporal_store(z, &o4[t + 256]);
    __builtin_nontemporal_store(z, &o4[t + 512]);
    __builtin_nontemporal_store(z, &o4[t + 768]);
  } else {
#pragma unroll
    for (int k = 0; k < 4; ++k) {
      const vf4 v = __builtin_nontemporal_load(&in4[t + k * 256]);
      vf4 r;
      r.x = g / (1.0f + __expf(-v.x));
      r.y = g / (1.0f + __expf(-v.y));
      r.z = g / (1.0f + __expf(-v.z));
      r.w = g / (1.0f + __expf(-v.w));
      __builtin_nontemporal_store(r, &o4[t + k * 256]);
    }
  }
}

// ---------------------------------------------------------------------------
extern "C" void kernel_launch(void* const* d_in, const int* in_sizes, int n_in,
                              void* d_out, int out_size, void* d_ws, size_t ws_size,
                              hipStream_t stream) {
  const float* logits = (const float*)d_in[0];
  const float* iou    = (const float*)d_in[1];

  float* out       = (float*)d_out;
  float* keep_out  = out + OUT_ELEMS;          // 1024 floats
  float* boxes_out = keep_out + NMASK;         // 4096 floats

  // workspace carve (24 KB)
  char* w = (char*)d_ws;
  float* score = (float*)(w);                  // 1024 f  -> 4096
  float* boxf  = (float*)(w + 4096);           // 4096 f  -> 20480 (16B aligned)
  float* gated = (float*)(w + 20480);          // 1024 f  -> 24576

  stats_kernel<<<NMASK, 256, 0, stream>>>(logits, iou, score, boxf, boxes_out);
  nms_fused<<<1, 1024, 0, stream>>>(score, boxf, iou, gated, keep_out);
  out_kernel<<<NMASK * 16, 256, 0, stream>>>(logits, gated, out);
}